// Round 9
// baseline (309.701 us; speedup 1.0000x reference)
//
#include <hip/hip_runtime.h>

#define B_   8
#define C_   128
#define H_   128
#define W_   128
#define HW_  16384

typedef short v8s __attribute__((ext_vector_type(8)));
typedef float v4f __attribute__((ext_vector_type(4)));

// LDS B-tile row: 130 px-slots x 32B (16ch bf16). Row stride 4160 B.
#define ROWB 4160

__device__ __forceinline__ float bf2f(unsigned short u) {
  unsigned int v = ((unsigned int)u) << 16;
  float f; __builtin_memcpy(&f, &v, 4); return f;
}
__device__ __forceinline__ unsigned short f2us(float f) {
  unsigned int u; __builtin_memcpy(&u, &f, 4);
  u += 0x7fffu + ((u >> 16) & 1u);           // RNE
  return (unsigned short)(u >> 16);
}

// ---- prep: transpose_x + both weight packs + zero scratch, one launch -------
// blocks [0,4096): transpose x fp32 [b][c][i][j] -> bf16 [b][cg][i][j][16c]
// blocks [4096,5376): pack w_off (G=16); [5376,6016): pack w_conv (G=8)
__global__ __launch_bounds__(256) void prep(const float* __restrict__ x,
                                            unsigned short* __restrict__ xt,
                                            const float* __restrict__ w_off,
                                            const float* __restrict__ w_conv,
                                            unsigned short* __restrict__ pack_off,
                                            unsigned short* __restrict__ pack_main,
                                            uint4* __restrict__ zb) {
  __shared__ alignas(16) unsigned short t[32 * 132];
  const int bid = blockIdx.x, tid = threadIdx.x;
  if (bid < 4096) {
    const int j0 = (bid & 3) * 32, i = (bid >> 2) & 127, b = bid >> 9;
    for (int e = tid; e < 1024; e += 256) {        // float4: 16B/lane, coalesced
      int c = e >> 3, j4 = (e & 7) << 2;
      float4 v = *(const float4*)&x[((b * C_ + c) * H_ + i) * W_ + j0 + j4];
      t[(j4 + 0) * 132 + c] = f2us(v.x);
      t[(j4 + 1) * 132 + c] = f2us(v.y);
      t[(j4 + 2) * 132 + c] = f2us(v.z);
      t[(j4 + 3) * 132 + c] = f2us(v.w);
    }
    __syncthreads();
    for (int f = tid; f < 1024; f += 256) {        // coalesced: 4 thr = 32B of one px
      int cg = f >> 7, g = f & 127;
      int j = g >> 2, c4 = (g & 3) << 2;
      uint2 v = *(const uint2*)&t[j * 132 + cg * 16 + c4];
      *(uint2*)(xt + ((size_t)(b * 8 + cg) * HW_ + i * W_ + j0 + j) * 16 + c4) = v;
    }
    return;
  }
  const int pb = bid - 4096;
  if (pb == 0) zb[tid] = (uint4){0u, 0u, 0u, 0u};  // 4 KB zeros
  const float* w;
  unsigned short* pack;
  int G, idx;
  if (pb < 1280) { w = w_off;  pack = pack_off;  G = 16; idx = pb * 256 + tid; }
  else           { w = w_conv; pack = pack_main; G = 8;  idx = (pb - 1280) * 256 + tid; }
  if (idx >= 20480 * G) return;
  int j  = idx & 7;
  int l  = (idx >> 3) & 63;
  int g  = (idx >> 9) % G;
  int t2 = idx / (512 * G);
  int pp = t2 % 5;
  int cc = t2 / 5;
  int oc = g * 16 + (l & 15);
  int kk = ((l >> 4) << 3) + j;
  int ic = (cc << 4) + (kk & 15);
  int rs = pp * 2 + (kk >> 4);
  float v = (rs < 9) ? w[(oc * C_ + ic) * 9 + rs] : 0.f;
  pack[idx] = f2us(v);
}

// ---------------- implicit-GEMM conv via MFMA + fused deform epilogue --------
// 8-wave / 2-output-row geometry, proven R3 inner loop, (512,4) reg cap.
// MODE 0 (offsets conv + FUSED DEFORM): the offsets needed for deform output
//   row i live at conv rows {2*(i%64), 2*(i%64)+1}, channel 2c+(i>=64) -- i.e.
//   exactly this block's own output (rows 2ip,2ip+1; ch [mt*128,+128)). So:
//   acc -> LDS bf16 tile [oc_l 128][r 2][col 132pad], barrier, then bilinear-
//   deform rows ip and ip+64 for c in [mt*64,+64), writing xoff_t directly.
//   Eliminates the 64MB offs write + 64MB read + the deform_t kernel.
// MODE 1: +bias+relu+BN partials (unchanged).
template <int MODE, int G>
__global__ __launch_bounds__(512, 4) void conv_gemm(const unsigned short* __restrict__ xt,
                                                    const unsigned short* __restrict__ pack,
                                                    const float* __restrict__ bias,
                                                    const char* __restrict__ zb,
                                                    const float* __restrict__ x,
                                                    unsigned short* __restrict__ outp,
                                                    float* __restrict__ ps) {
  // union: staging tile (16640 B) during K-loop; MODE0 epilogue reuses as
  // offs tile 128*264 u16 = 67584 B (dead staging). 2 blocks/CU either way.
  __shared__ alignas(16) char rawb[MODE == 0 ? 67584 : 16640];
  __shared__ float bs1[128], bs2[128];

  const int nb = blockIdx.x;
  int b, ip, mt;
  {
    int xcd = nb & 7, r = nb >> 3;
    if (MODE == 0) { b = r >> 4; mt = (r >> 3) & 1; ip = xcd * 8 + (r & 7); }
    else           { b = r >> 3; mt = 0;            ip = xcd * 8 + (r & 7); }
  }
  const int i0 = ip * 2;                           // output rows i0, i0+1
  const int tid  = threadIdx.x;
  const int lane = tid & 63, wid = tid >> 6;       // wid 0..7
  const int q = lane >> 4, n = lane & 15;
  const int wr = wid & 1, wm = (wid >> 1) & 1, wn = wid >> 2;  // wn 0..1

  if (MODE == 1 && tid < 128) { bs1[tid] = 0.f; bs2[tid] = 0.f; }
  // halo-edge slots (px -1 / 128) of the 4 staged rows are always zero
  if (tid < 16) {
    int r = tid >> 2, rem = tid & 3, side = rem >> 1, h = rem & 1;
    *(uint4*)(rawb + r * ROWB + (side ? 129 * 32 : 0) + h * 16) = (uint4){0u,0u,0u,0u};
  }

  // per-pp LDS base: rs -> (staged row wr+dr, col s), 32B px stride,
  // (q&1) picks 16B half
  int boff[5];
#pragma unroll
  for (int pp = 0; pp < 5; ++pp) {
    int rs = pp * 2 + (q >> 1);
    if (rs > 8) rs = 8;                            // pad half: A is zero there
    int dr = (rs >= 6) ? 2 : ((rs >= 3) ? 1 : 0);
    int s = rs - dr * 3;
    boff[pp] = (wr + dr) * ROWB + s * 32 + (q & 1) * 16;
  }
  const int pcol = (wn * 64 + n) * 32;

  v4f acc[4][4];
#pragma unroll
  for (int a = 0; a < 4; ++a)
#pragma unroll
    for (int c = 0; c < 4; ++c) acc[a][c] = (v4f){0.f, 0.f, 0.f, 0.f};

  const v8s* packv = (const v8s*)pack;
  const int gbase = mt * 8 + wm * 4;

  for (int cc = 0; cc < 8; ++cc) {
    __syncthreads();                               // prev compute done
    // stage 4 halo rows (16 x 1KB chunks; wave w -> chunks 2w, 2w+1)
    const char* ccbase = (const char*)xt + (size_t)(b * 8 + cc) * (HW_ * 32);
#pragma unroll
    for (int t = 0; t < 2; ++t) {
      int c = wid * 2 + t, r = c >> 2, k = c & 3;
      int ii = i0 + r - 1;
      const char* src = ((unsigned)ii < 128u)
                          ? ccbase + ii * 4096 + k * 1024 + lane * 16
                          : zb + lane * 16;
      __builtin_amdgcn_global_load_lds(
          (const __attribute__((address_space(1))) unsigned int*)src,
          (__attribute__((address_space(3))) unsigned int*)(rawb + r * ROWB + 32 + k * 1024),
          16, 0, 0);
    }
    __syncthreads();                               // vmcnt drain: DMA visible

#pragma unroll
    for (int pp = 0; pp < 5; ++pp) {
      const v8s* ap = packv + ((cc * 5 + pp) * G + gbase) * 64 + lane;
      v8s Af[4];
#pragma unroll
      for (int fm = 0; fm < 4; ++fm) Af[fm] = ap[fm * 64];
      v8s Bf[4];
#pragma unroll
      for (int fn = 0; fn < 4; ++fn)
        Bf[fn] = *(const v8s*)(rawb + boff[pp] + pcol + fn * 512);
#pragma unroll
      for (int fm = 0; fm < 4; ++fm) {
#pragma unroll
        for (int fn = 0; fn < 4; ++fn)
          acc[fm][fn] = __builtin_amdgcn_mfma_f32_16x16x32_bf16(Af[fm], Bf[fn],
                                                                acc[fm][fn], 0, 0, 0);
      }
    }
  }

  if (MODE == 0) {
    // -------- fused deform epilogue --------
    unsigned short* ot = (unsigned short*)rawb;    // [oc_l 128][r 2][col 132]
    __syncthreads();                               // staging reads done
#pragma unroll
    for (int fm = 0; fm < 4; ++fm)
#pragma unroll
      for (int fn = 0; fn < 4; ++fn)
#pragma unroll
        for (int rr = 0; rr < 4; ++rr) {
          int oc_l = wm * 64 + fm * 16 + q * 4 + rr;
          int col  = wn * 64 + fn * 16 + n;
          ot[oc_l * 264 + wr * 132 + col] = f2us(acc[fm][fn][rr]);
        }
    __syncthreads();
    const float* xb = x + (((size_t)b * C_) << 14);
    for (int s = tid; s < 1024; s += 512) {        // (cgl 4) x (isel 2) x (px 128)
      int px = s & 127, isel = (s >> 7) & 1, cgl = s >> 8;
      int di = ip + isel * 64;                     // deform output row
      const float fi = (float)di, fj = (float)px;
      int cy = 2 * px, cx = 2 * px + 1;            // quirky-reshape u16 columns
      int ry = cy >> 7, coly = cy & 127;
      int rx = cx >> 7, colx = cx & 127;
      unsigned int packed[8];
#pragma unroll
      for (int u = 0; u < 16; ++u) {
        int c_l = cgl * 16 + u;
        int chl = 2 * c_l + isel;                  // local conv-out channel
        float oy = bf2f(ot[chl * 264 + ry * 132 + coly]);
        float ox = bf2f(ot[chl * 264 + rx * 132 + colx]);
        float yc = fminf(fmaxf(oy + fi, 0.f), 127.f);
        float xc = fminf(fmaxf(ox + fj, 0.f), 127.f);
        float y0f = floorf(yc), y1f = ceilf(yc);
        float x0f = floorf(xc), x1f = ceilf(xc);
        int y0 = (int)y0f, y1 = (int)y1f, x0 = (int)x0f, x1 = (int)x1f;
        const float* img = xb + ((mt * 64 + c_l) << 14);
        float v_lt = img[y0 * W_ + x0];
        float v_rb = img[y1 * W_ + x1];
        float v_lb = img[y0 * W_ + x1];
        float v_rt = img[y1 * W_ + x0];
        float dy = yc - y0f, dx = xc - x0f;
        float v_t = v_lt + (v_rt - v_lt) * dy;
        float v_b = v_lb + (v_rb - v_lb) * dy;
        float o   = v_t + (v_b - v_t) * dx;
        unsigned int us = (unsigned int)f2us(o);
        if (u & 1) packed[u >> 1] |= us << 16;
        else       packed[u >> 1]  = us;
      }
      unsigned short* dst =
          outp + ((size_t)((b * 8 + mt * 4 + cgl) * HW_ + di * W_ + px) << 4);
      ((uint4*)dst)[0] = (uint4){packed[0], packed[1], packed[2], packed[3]};
      ((uint4*)dst)[1] = (uint4){packed[4], packed[5], packed[6], packed[7]};
    }
  } else {
    const int OC = G * 16;
    const int ob = (b * OC + mt * 128 + wm * 64) * HW_ + (i0 + wr) * W_ + wn * 64;
    float bv[4][4], s1a[4][4], s2a[4][4];
#pragma unroll
    for (int fm = 0; fm < 4; ++fm)
#pragma unroll
      for (int rr = 0; rr < 4; ++rr) {
        bv[fm][rr] = bias[wm * 64 + fm * 16 + q * 4 + rr];
        s1a[fm][rr] = 0.f; s2a[fm][rr] = 0.f;
      }
#pragma unroll
    for (int fm = 0; fm < 4; ++fm)
#pragma unroll
      for (int fn = 0; fn < 4; ++fn)
#pragma unroll
        for (int rr = 0; rr < 4; ++rr) {
          float v = acc[fm][fn][rr] + bv[fm][rr];
          v = fmaxf(v, 0.f);
          outp[ob + (fm * 16 + q * 4 + rr) * HW_ + fn * 16 + n] = f2us(v);
          s1a[fm][rr] += v; s2a[fm][rr] += v * v;
        }
#pragma unroll
    for (int fm = 0; fm < 4; ++fm)
#pragma unroll
      for (int rr = 0; rr < 4; ++rr) {
        float s1 = s1a[fm][rr], s2 = s2a[fm][rr];
#pragma unroll
        for (int m = 1; m < 16; m <<= 1) {
          s1 += __shfl_xor(s1, m);
          s2 += __shfl_xor(s2, m);
        }
        if (n == 0) {
          atomicAdd(&bs1[wm * 64 + fm * 16 + q * 4 + rr], s1);
          atomicAdd(&bs2[wm * 64 + fm * 16 + q * 4 + rr], s2);
        }
      }
    __syncthreads();
    if (tid < 128) {
      ps[nb * 128 + tid]          = bs1[tid];
      ps[131072 + nb * 128 + tid] = bs2[tid];
    }
  }
}

// ---------------- BN finalize: fold stats into scale/shift -------------------
__global__ __launch_bounds__(256) void bn_finalize(const float* __restrict__ ps,
                                                   const float* __restrict__ gamma,
                                                   const float* __restrict__ beta,
                                                   float* __restrict__ stats) {
  const int c = blockIdx.x, tid = threadIdx.x;
  float s1 = 0.f, s2 = 0.f;
  for (int k = tid; k < 512; k += 256) {
    s1 += ps[k * 128 + c];
    s2 += ps[131072 + k * 128 + c];
  }
#pragma unroll
  for (int m = 32; m > 0; m >>= 1) {
    s1 += __shfl_down(s1, m);
    s2 += __shfl_down(s2, m);
  }
  __shared__ float l1[4], l2[4];
  int wid = tid >> 6;
  if ((tid & 63) == 0) { l1[wid] = s1; l2[wid] = s2; }
  __syncthreads();
  if (tid == 0) {
    s1 = l1[0] + l1[1] + l1[2] + l1[3];
    s2 = l2[0] + l2[1] + l2[2] + l2[3];
    const float invn = 1.f / 131072.f;
    float mean = s1 * invn;
    float var  = s2 * invn - mean * mean;
    float inv  = rsqrtf(var + 1e-5f);
    float sc = gamma[c] * inv;
    stats[c]       = sc;
    stats[128 + c] = beta[c] - mean * sc;
  }
}

// ---------------- BN apply: bf16 y -> fp32 out, 16 elems/thread --------------
__global__ __launch_bounds__(256) void bn_apply(const unsigned short* __restrict__ y,
                                                const float* __restrict__ stats,
                                                float* __restrict__ out) {
  int gid = blockIdx.x * 256 + threadIdx.x;
  int base = gid << 4;                             // 16 bf16, same channel
  int c = (base >> 14) & 127;
  float sc = stats[c], sh = stats[128 + c];
  uint4 u0 = ((const uint4*)y)[gid * 2];
  uint4 u1 = ((const uint4*)y)[gid * 2 + 1];
  const unsigned short* us0 = (const unsigned short*)&u0;
  const unsigned short* us1 = (const unsigned short*)&u1;
  float4 o[4];
#pragma unroll
  for (int k = 0; k < 4; ++k) {
    const unsigned short* s = (k < 2) ? us0 + k * 4 : us1 + (k - 2) * 4;
    o[k].x = bf2f(s[0]) * sc + sh;
    o[k].y = bf2f(s[1]) * sc + sh;
    o[k].z = bf2f(s[2]) * sc + sh;
    o[k].w = bf2f(s[3]) * sc + sh;
  }
#pragma unroll
  for (int k = 0; k < 4; ++k) ((float4*)out)[gid * 4 + k] = o[k];
}

// ---------------- launch -----------------------------------------------------
extern "C" void kernel_launch(void* const* d_in, const int* in_sizes, int n_in,
                              void* d_out, int out_size, void* d_ws, size_t ws_size,
                              hipStream_t stream) {
  const float* x      = (const float*)d_in[0];
  const float* w_off  = (const float*)d_in[1];
  const float* w_conv = (const float*)d_in[2];
  const float* b_conv = (const float*)d_in[3];
  const float* gamma  = (const float*)d_in[4];
  const float* beta   = (const float*)d_in[5];
  float* out = (float*)d_out;

  char* ws = (char*)d_ws;
  unsigned short* x_t    = (unsigned short*)ws;            // 32M; dead after conv0
  unsigned short* xoff_t = (unsigned short*)(ws + 33554432); // 32M (was offs)
  unsigned short* yws    = (unsigned short*)ws;            // aliases dead x_t
  float* ps    = (float*)(ws + 67108864);
  float* stats = (float*)(ws + 68157440);
  unsigned short* pack_off  = (unsigned short*)(ws + 100663296);  // 640 KB
  unsigned short* pack_main = (unsigned short*)(ws + 101318656);  // 320 KB
  char* zb = ws + 101646336;                               // 4 KB zeros

  prep<<<6016, 256, 0, stream>>>(x, x_t, w_off, w_conv, pack_off, pack_main,
                                 (uint4*)zb);
  conv_gemm<0, 16><<<1024, 512, 0, stream>>>(x_t, pack_off, nullptr, zb, x,
                                             xoff_t, nullptr);
  conv_gemm<1, 8><<<512, 512, 0, stream>>>(xoff_t, pack_main, b_conv, zb, nullptr,
                                           yws, ps);
  bn_finalize<<<128, 256, 0, stream>>>(ps, gamma, beta, stats);
  bn_apply<<<4096, 256, 0, stream>>>(yws, stats, out);
}